// Round 12
// baseline (4076.057 us; speedup 1.0000x reference)
//
#include <hip/hip_runtime.h>
#include <hip/hip_bf16.h>
#include <stdint.h>

#define T_STEPS 512
#define BATCH   64
#define DIN     512
#define DLAT    1024
#define NWG     128          // 64 col-tiles x 2 chain-pair slots

typedef __bf16 bf16_t;
typedef __bf16 bf16x4 __attribute__((ext_vector_type(4)));
typedef __bf16 bf16x8 __attribute__((ext_vector_type(8)));
typedef float  f32x4  __attribute__((ext_vector_type(4)));

// ---- workspace layout (bytes) ----
#define XB_OFF     0u                        // bf16 x [512][64][512] = 33,554,432
#define WXT_OFF    33554432u                 // bf16 x-weights frag-ordered = 4,194,304
#define FLAGS_OFF  (WXT_OFF + 4194304u)      // u32 flags[513][4][64] = 525,312
#define HS_OFF     (FLAGS_OFF + 525312u)     // bf16 h ring [2][64][1024] = 262,144
#define SLOT_ELEMS 65536
#define MEMSET_BYTES (525312u + 262144u)     // flags + both h slots

// ---- LDS layout (bytes) ----
#define HW_OFF_B   0          // h-weights [64 cols][1024 k] bf16, swizzled = 131,072
#define PART_OFF_B 131072     // f32 [4 waves][64 cols][20 rows-pad] = 20,480
#define LDS_BYTES  152064     // forces 1 WG/CU

__global__ void xconv_kernel(const float* __restrict__ x, bf16_t* __restrict__ xb) {
    size_t i = ((size_t)blockIdx.x * 256 + threadIdx.x) * 4;
    const float4 v = *(const float4*)(x + i);
    bf16x4 o;
    o[0] = (bf16_t)v.x; o[1] = (bf16_t)v.y; o[2] = (bf16_t)v.z; o[3] = (bf16_t)v.w;
    *(bf16x4*)(xb + i) = o;
}

// x-weight prep (frag order, as R10/R11 — verified)
__global__ void wxt_prep(const float* __restrict__ Wf, const float* __restrict__ Wi,
                         const float* __restrict__ Wo, const float* __restrict__ Wu,
                         bf16_t* __restrict__ wxt) {
    const int gid  = blockIdx.x * 256 + threadIdx.x;   // 0..262143
    const int lane = gid & 63;
    const int f    = gid >> 6;
    const int cf   = f & 3;
    const int ks   = (f >> 2) & 3;
    const int wv   = (f >> 4) & 3;
    const int ct   = f >> 6;
    const float* Wg = (cf == 0) ? Wf : (cf == 1) ? Wi : (cf == 2) ? Wo : Wu;
    const int k0 = wv * 128 + ks * 32 + (lane >> 4) * 8;
    const int j  = ct * 16 + (lane & 15);
    bf16x8 v;
#pragma unroll
    for (int e = 0; e < 8; ++e) v[e] = (bf16_t)Wg[(size_t)(k0 + e) * DLAT + j];
    *(bf16x8*)(wxt + (size_t)gid * 8) = v;
}

__device__ __forceinline__ float rcp_(float x) { return __builtin_amdgcn_rcpf(x); }
__device__ __forceinline__ float sigmoidf_(float v) { return rcp_(1.f + __expf(-v)); }
__device__ __forceinline__ float tanh_fast(float x) {
    const float ax = fabsf(x);
    const float e  = __expf(-2.f * ax);
    const float t  = (1.f - e) * rcp_(1.f + e);
    return copysignf(t, x);
}

__device__ __forceinline__ bf16x8 ldsHW(const char* lds, int c, int kh, int lq) {
    const uint32_t off = (uint32_t)(c * 2048 + kh * 2 + lq * 16)
                       ^ (uint32_t)((c & 7) << 4);
    return *(const bf16x8*)(lds + HW_OFF_B + off);
}

__device__ __forceinline__ bf16x8 ldh16_sc1(const bf16_t* p) {
    f32x4 r;
    asm volatile("global_load_dwordx4 %0, %1, off sc1"
                 : "=v"(r) : "v"(p) : "memory");
    return __builtin_bit_cast(bf16x8, r);
}

__device__ __forceinline__ void sth2(bf16_t* p, bf16_t v) {
    const uint32_t d = (uint32_t)__builtin_bit_cast(uint16_t, v);
    asm volatile("global_store_short %0, %1, off sc1"
                 :: "v"(p), "v"(d) : "memory");
}

__device__ __forceinline__ void stflag(uint32_t* p, uint32_t v) {
    asm volatile("global_store_dword %0, %1, off sc1" :: "v"(p), "v"(v) : "memory");
}

// one full step of ONE chain (row-block rb), R10/R11-proven protocol
__device__ __forceinline__ void step_phase(
    const int t, const int rb, const char* ldsraw, float* part,
    const bf16_t* __restrict__ xb, const bf16_t* __restrict__ wx_base,
    bf16_t* __restrict__ hslots, uint32_t* __restrict__ flags,
    float* __restrict__ out,
    const int tid, const int wv, const int lm, const int lq,
    const int row_l, const int jj, const int j0, const int ct,
    const float bias_r[4], float& cst, f32x4 (&acc)[4])
{
    const int r0 = rb * 16;
    const int lane_in_wave = lq * 16 + lm;
    const bf16_t* hprev = hslots + (size_t)(t & 1) * SLOT_ELEMS;
    bf16_t*       hnext = hslots + (size_t)((t + 1) & 1) * SLOT_ELEMS;

    // per-wave narrowed poll (16 producers of this wave's k-slice, this chain)
    if (t > 0) {
        const uint32_t* fp = flags + ((size_t)t * 4 + rb) * 64 + (uint32_t)(wv * 16 + lm);
        while (true) {
            uint32_t v;
            asm volatile("global_load_dword %0, %1, off sc1\n\ts_waitcnt vmcnt(0)"
                         : "=v"(v) : "v"(fp) : "memory");
            if (__all(v == 1u)) break;
        }
        asm volatile("" ::: "memory");
    } else {
        asm volatile("s_waitcnt vmcnt(0)" ::: "memory");   // clean vmcnt baseline
    }

    // h GEMM: 8 sc1 16B loads, two-stage vmcnt; B-frags from LDS
    {
        const bf16_t* hb = hprev + (size_t)(r0 + lm) * DLAT + wv * 256 + lq * 8;
        bf16x8 ha[8];
#pragma unroll
        for (int ks = 0; ks < 8; ++ks) ha[ks] = ldh16_sc1(hb + ks * 32);
        asm volatile("s_waitcnt vmcnt(4)" ::: "memory");
        __builtin_amdgcn_sched_barrier(0);
#pragma unroll
        for (int ks = 0; ks < 4; ++ks) {
            const int kh = wv * 256 + ks * 32;
#pragma unroll
            for (int cf = 0; cf < 4; ++cf) {
                const bf16x8 b = ldsHW(ldsraw, cf * 16 + lm, kh, lq);
                acc[cf] = __builtin_amdgcn_mfma_f32_16x16x32_bf16(ha[ks], b, acc[cf], 0, 0, 0);
            }
        }
        asm volatile("s_waitcnt vmcnt(0)" ::: "memory");
        __builtin_amdgcn_sched_barrier(0);
#pragma unroll
        for (int ks = 4; ks < 8; ++ks) {
            const int kh = wv * 256 + ks * 32;
#pragma unroll
            for (int cf = 0; cf < 4; ++cf) {
                const bf16x8 b = ldsHW(ldsraw, cf * 16 + lm, kh, lq);
                acc[cf] = __builtin_amdgcn_mfma_f32_16x16x32_bf16(ha[ks], b, acc[cf], 0, 0, 0);
            }
        }
    }

    // cross-wave K-reduction via LDS
#pragma unroll
    for (int cf = 0; cf < 4; ++cf)
        *(f32x4*)&part[(wv * 64 + cf * 16 + lm) * 20 + lq * 4] = acc[cf];
    __syncthreads();   // barrier #1

    float gs[4];
#pragma unroll
    for (int g = 0; g < 4; ++g) {
        const int c = g * 16 + jj;
        gs[g] = part[(0 * 64 + c) * 20 + row_l] + part[(1 * 64 + c) * 20 + row_l]
              + part[(2 * 64 + c) * 20 + row_l] + part[(3 * 64 + c) * 20 + row_l]
              + bias_r[g];
    }
    const float ft = sigmoidf_(gs[0]);
    const float it = sigmoidf_(gs[1]);
    const float ot = sigmoidf_(gs[2]);
    const float ut = tanh_fast(gs[3]);
    cst = ft * cst + it * ut;
    const float hv = ot * tanh_fast(cst);

    // direct per-thread 2B sc1 publish, drain, bar, flag
    sth2(hnext + (size_t)(r0 + row_l) * DLAT + j0 + jj, (bf16_t)hv);
    asm volatile("s_waitcnt vmcnt(0)" ::: "memory");
    __syncthreads();   // barrier #2: publishes drained + part reads complete
    if (tid == 0)
        stflag(flags + ((size_t)(t + 1) * 4 + rb) * 64 + ct, 1u);

    // out store (cached path)
    out[((size_t)t * BATCH + r0 + row_l) * DLAT + j0 + jj] = hv;

    // overlap: x_{t+1} GEMM into fresh acc (fills the chain-latency shadow)
#pragma unroll
    for (int cf = 0; cf < 4; ++cf) acc[cf] = (f32x4){0.f, 0.f, 0.f, 0.f};
    if (t + 1 < T_STEPS) {
        const bf16_t* xa = xb + (size_t)(t + 1) * (BATCH * DIN)
                         + (size_t)(r0 + lm) * DIN + wv * 128 + lq * 8;
#pragma unroll
        for (int ks = 0; ks < 4; ++ks) {
            const bf16x8 a = *(const bf16x8*)(xa + ks * 32);
#pragma unroll
            for (int cf = 0; cf < 4; ++cf) {
                const bf16x8 b = *(const bf16x8*)(wx_base + (ks * 4 + cf) * 512 + lane_in_wave * 8);
                acc[cf] = __builtin_amdgcn_mfma_f32_16x16x32_bf16(a, b, acc[cf], 0, 0, 0);
            }
        }
    }
}

__launch_bounds__(256, 1)
__global__ void lstm_main(const float* __restrict__ Wf, const float* __restrict__ Wi,
                          const float* __restrict__ Wo, const float* __restrict__ Wu,
                          const float* __restrict__ bfp, const float* __restrict__ bip,
                          const float* __restrict__ bop, const float* __restrict__ bup,
                          const bf16_t* __restrict__ xb,
                          const bf16_t* __restrict__ wxt,
                          bf16_t* __restrict__ hslots,
                          uint32_t* __restrict__ flags,
                          float* __restrict__ out) {
    extern __shared__ char ldsraw[];
    float* part = (float*)(ldsraw + PART_OFF_B);

    const int tid  = threadIdx.x;
    const int wv   = tid >> 6;
    const int lane = tid & 63;
    const int lm   = lane & 15;
    const int lq   = lane >> 4;
    const int ct   = blockIdx.x >> 1;     // col-tile 0..63
    const int pb   = blockIdx.x & 1;      // chain pair: rbA = pb, rbB = pb+2
    const int rbA  = pb;
    const int rbB  = pb + 2;
    const int j0   = ct * 16;

    // one-time: h-weights -> LDS (shared by both chains; same col-tile)
    {
        const int c    = tid & 63;
        const int jj_  = c & 15;
        const int gate = c >> 4;
        const float* Wg = (gate == 0) ? Wf : (gate == 1) ? Wi : (gate == 2) ? Wo : Wu;
        const float* src = Wg + (size_t)512 * DLAT + (j0 + jj_);
        for (int kb = tid >> 6; kb < 128; kb += 4) {
            const int k0 = kb * 8;
            bf16x8 v;
#pragma unroll
            for (int e = 0; e < 8; ++e) v[e] = (bf16_t)src[(size_t)(k0 + e) * DLAT];
            const uint32_t a = (uint32_t)(c * 2048 + kb * 16) ^ (uint32_t)((c & 7) << 4);
            *(bf16x8*)(ldsraw + HW_OFF_B + a) = v;
        }
    }

    const int row_l = tid >> 4;          // 0..15
    const int jj    = tid & 15;          // 0..15
    const float bias_r[4] = { bfp[j0 + jj], bip[j0 + jj], bop[j0 + jj], bup[j0 + jj] };
    float cstA = 0.f, cstB = 0.f;

    const bf16_t* wx_base = wxt + (size_t)((ct * 4 + wv) * 16) * 512;

    __syncthreads();   // weights visible

    f32x4 accA[4], accB[4];
#pragma unroll
    for (int cf = 0; cf < 4; ++cf) {
        accA[cf] = (f32x4){0.f, 0.f, 0.f, 0.f};
        accB[cf] = (f32x4){0.f, 0.f, 0.f, 0.f};
    }

    // prologue: x_0 GEMM for both chains
#pragma unroll
    for (int ks = 0; ks < 4; ++ks) {
        const bf16x8 aA = *(const bf16x8*)(xb + (size_t)(rbA * 16 + lm) * DIN + wv * 128 + ks * 32 + lq * 8);
        const bf16x8 aB = *(const bf16x8*)(xb + (size_t)(rbB * 16 + lm) * DIN + wv * 128 + ks * 32 + lq * 8);
#pragma unroll
        for (int cf = 0; cf < 4; ++cf) {
            const bf16x8 b = *(const bf16x8*)(wx_base + (ks * 4 + cf) * 512 + lane * 8);
            accA[cf] = __builtin_amdgcn_mfma_f32_16x16x32_bf16(aA, b, accA[cf], 0, 0, 0);
            accB[cf] = __builtin_amdgcn_mfma_f32_16x16x32_bf16(aB, b, accB[cf], 0, 0, 0);
        }
    }

    for (int t = 0; t < T_STEPS; ++t) {
        step_phase(t, rbA, ldsraw, part, xb, wx_base, hslots, flags, out,
                   tid, wv, lm, lq, row_l, jj, j0, ct, bias_r, cstA, accA);
        step_phase(t, rbB, ldsraw, part, xb, wx_base, hslots, flags, out,
                   tid, wv, lm, lq, row_l, jj, j0, ct, bias_r, cstB, accB);
    }
}

extern "C" void kernel_launch(void* const* d_in, const int* in_sizes, int n_in,
                              void* d_out, int out_size, void* d_ws, size_t ws_size,
                              hipStream_t stream) {
    const float* x  = (const float*)d_in[0];
    const float* Wf = (const float*)d_in[1];
    const float* Wi = (const float*)d_in[2];
    const float* Wo = (const float*)d_in[3];
    const float* Wu = (const float*)d_in[4];
    const float* bf = (const float*)d_in[5];
    const float* bi = (const float*)d_in[6];
    const float* bo = (const float*)d_in[7];
    const float* bu = (const float*)d_in[8];
    float* out = (float*)d_out;

    char* ws = (char*)d_ws;
    bf16_t*   xb     = (bf16_t*)(ws + XB_OFF);
    bf16_t*   wxt    = (bf16_t*)(ws + WXT_OFF);
    uint32_t* flags  = (uint32_t*)(ws + FLAGS_OFF);
    bf16_t*   hslots = (bf16_t*)(ws + HS_OFF);

    (void)hipMemsetAsync(ws + FLAGS_OFF, 0, MEMSET_BYTES, stream);

    xconv_kernel<<<16384, 256, 0, stream>>>(x, xb);
    wxt_prep<<<1024, 256, 0, stream>>>(Wf, Wi, Wo, Wu, wxt);

    (void)hipFuncSetAttribute((const void*)lstm_main,
                              hipFuncAttributeMaxDynamicSharedMemorySize, LDS_BYTES);

    lstm_main<<<NWG, 256, LDS_BYTES, stream>>>(Wf, Wi, Wo, Wu, bf, bi, bo, bu,
                                               xb, wxt, hslots, flags, out);
}

// Round 13
// 2072.745 us; speedup vs baseline: 1.9665x; 1.9665x over previous
//
#include <hip/hip_runtime.h>
#include <hip/hip_bf16.h>
#include <stdint.h>

#define T_STEPS 512
#define BATCH   64
#define DIN     512
#define DLAT    1024
#define NWG     256          // 64 col-tiles x 4 row-blocks
#define NSLOT   64           // h slot ring (zero = not-yet-written protocol)

typedef __bf16 bf16_t;
typedef __bf16 bf16x4 __attribute__((ext_vector_type(4)));
typedef __bf16 bf16x8 __attribute__((ext_vector_type(8)));
typedef float  f32x4  __attribute__((ext_vector_type(4)));
typedef uint32_t u32x4 __attribute__((ext_vector_type(4)));

// ---- workspace layout (bytes) ----
#define XB_OFF     0u                        // bf16 x [512][64][512] = 33,554,432
#define WXT_OFF    33554432u                 // bf16 x-weights frag-ordered = 4,194,304
#define HS_OFF     (WXT_OFF + 4194304u)      // bf16 h slots [64][64][1024] = 8,388,608
#define SLOT_ELEMS 65536
#define MEMSET_BYTES 8388608u                // all 64 slots -> 0 every launch

// ---- LDS layout (bytes) ----
#define HW_OFF_B   0          // h-weights [64 cols][1024 k] bf16, swizzled = 131,072
#define PART_OFF_B 131072     // f32 [4 waves][64 cols][20 rows-pad] = 20,480
#define LDS_BYTES  152064     // forces 1 WG/CU

__global__ void xconv_kernel(const float* __restrict__ x, bf16_t* __restrict__ xb) {
    size_t i = ((size_t)blockIdx.x * 256 + threadIdx.x) * 4;
    const float4 v = *(const float4*)(x + i);
    bf16x4 o;
    o[0] = (bf16_t)v.x; o[1] = (bf16_t)v.y; o[2] = (bf16_t)v.z; o[3] = (bf16_t)v.w;
    *(bf16x4*)(xb + i) = o;
}

// x-weight prep (frag order, verified R10/R11)
__global__ void wxt_prep(const float* __restrict__ Wf, const float* __restrict__ Wi,
                         const float* __restrict__ Wo, const float* __restrict__ Wu,
                         bf16_t* __restrict__ wxt) {
    const int gid  = blockIdx.x * 256 + threadIdx.x;   // 0..262143
    const int lane = gid & 63;
    const int f    = gid >> 6;
    const int cf   = f & 3;
    const int ks   = (f >> 2) & 3;
    const int wv   = (f >> 4) & 3;
    const int ct   = f >> 6;
    const float* Wg = (cf == 0) ? Wf : (cf == 1) ? Wi : (cf == 2) ? Wo : Wu;
    const int k0 = wv * 128 + ks * 32 + (lane >> 4) * 8;
    const int j  = ct * 16 + (lane & 15);
    bf16x8 v;
#pragma unroll
    for (int e = 0; e < 8; ++e) v[e] = (bf16_t)Wg[(size_t)(k0 + e) * DLAT + j];
    *(bf16x8*)(wxt + (size_t)gid * 8) = v;
}

__device__ __forceinline__ float rcp_(float x) { return __builtin_amdgcn_rcpf(x); }
__device__ __forceinline__ float sigmoidf_(float v) { return rcp_(1.f + __expf(-v)); }
__device__ __forceinline__ float tanh_fast(float x) {
    const float ax = fabsf(x);
    const float e  = __expf(-2.f * ax);
    const float t  = (1.f - e) * rcp_(1.f + e);
    return copysignf(t, x);
}

__device__ __forceinline__ bf16x8 ldsHW(const char* lds, int c, int kh, int lq) {
    const uint32_t off = (uint32_t)(c * 2048 + kh * 2 + lq * 16)
                       ^ (uint32_t)((c & 7) << 4);
    return *(const bf16x8*)(lds + HW_OFF_B + off);
}

// sc1 (MALL-coherent) 16B load, issued without wait
__device__ __forceinline__ bf16x8 ldh16_sc1(const bf16_t* p) {
    f32x4 r;
    asm volatile("global_load_dwordx4 %0, %1, off sc1"
                 : "=v"(r) : "v"(p) : "memory");
    return __builtin_bit_cast(bf16x8, r);
}

// device-scope 2B write-through store
__device__ __forceinline__ void sth2u(bf16_t* p, uint32_t bits) {
    asm volatile("global_store_short %0, %1, off sc1"
                 :: "v"(p), "v"(bits) : "memory");
}

// raw WG barrier: LDS visibility only, does NOT drain vmcnt (keeps publish
// stores flying — the consumer detects them via the data itself)
__device__ __forceinline__ void bar_lds() {
    asm volatile("s_waitcnt lgkmcnt(0)" ::: "memory");
    __builtin_amdgcn_s_barrier();
    asm volatile("" ::: "memory");
}

__launch_bounds__(256, 1)
__global__ void lstm_main(const float* __restrict__ Wf, const float* __restrict__ Wi,
                          const float* __restrict__ Wo, const float* __restrict__ Wu,
                          const float* __restrict__ bfp, const float* __restrict__ bip,
                          const float* __restrict__ bop, const float* __restrict__ bup,
                          const bf16_t* __restrict__ xb,
                          const bf16_t* __restrict__ wxt,
                          bf16_t* __restrict__ hslots,
                          float* __restrict__ out) {
    extern __shared__ char ldsraw[];
    float* part = (float*)(ldsraw + PART_OFF_B);   // [4][64 cols][20 rows]

    const int tid  = threadIdx.x;
    const int wv   = tid >> 6;       // wave = k-slice
    const int lane = tid & 63;
    const int lm   = lane & 15;
    const int lq   = lane >> 4;
    const int rb   = blockIdx.x & 3;    // row-block: rows [rb*16, +16)
    const int ct   = blockIdx.x >> 2;   // col-tile: j [ct*16, +16), all 4 gates
    const int r0   = rb * 16;
    const int j0   = ct * 16;

    // ---- one-time: h-weights -> LDS [64 cols][1024 k] bf16, swizzled ----
    {
        const int c    = tid & 63;
        const int gate = c >> 4;
        const int jj_  = c & 15;
        const float* Wg = (gate == 0) ? Wf : (gate == 1) ? Wi : (gate == 2) ? Wo : Wu;
        const float* src = Wg + (size_t)512 * DLAT + (j0 + jj_);
        for (int kb = tid >> 6; kb < 128; kb += 4) {
            const int k0 = kb * 8;
            bf16x8 v;
#pragma unroll
            for (int e = 0; e < 8; ++e) v[e] = (bf16_t)src[(size_t)(k0 + e) * DLAT];
            const uint32_t a = (uint32_t)(c * 2048 + kb * 16) ^ (uint32_t)((c & 7) << 4);
            *(bf16x8*)(ldsraw + HW_OFF_B + a) = v;
        }
    }

    // elementwise ownership: tid = row_l*16 + jj
    const int row_l = tid >> 4;          // 0..15
    const int jj    = tid & 15;          // 0..15
    const float bias_r[4] = { bfp[j0 + jj], bip[j0 + jj], bop[j0 + jj], bup[j0 + jj] };
    float cst = 0.f;

    // per-wave x-weight base (frag-ordered, cached reads — read-only, safe)
    const bf16_t* wx_base = wxt + (size_t)((ct * 4 + wv) * 16) * 512;

    __syncthreads();   // weights visible

    f32x4 acc[4];
#pragma unroll
    for (int cf = 0; cf < 4; ++cf) acc[cf] = (f32x4){0.f, 0.f, 0.f, 0.f};

    // ---- prologue: x_0 GEMM (wave x-k slice [wv*128, +128)) ----
    {
        const bf16_t* xa = xb + (size_t)(r0 + lm) * DIN + wv * 128 + lq * 8;
#pragma unroll
        for (int ks = 0; ks < 4; ++ks) {
            const bf16x8 a = *(const bf16x8*)(xa + ks * 32);
#pragma unroll
            for (int cf = 0; cf < 4; ++cf) {
                const bf16x8 b = *(const bf16x8*)(wx_base + (ks * 4 + cf) * 512 + lane * 8);
                acc[cf] = __builtin_amdgcn_mfma_f32_16x16x32_bf16(a, b, acc[cf], 0, 0, 0);
            }
        }
    }

    for (int t = 0; t < T_STEPS; ++t) {
        const bf16_t* hprev = hslots + (size_t)(t & (NSLOT - 1)) * SLOT_ELEMS;
        bf16_t*       hnext = hslots + (size_t)((t + 1) & (NSLOT - 1)) * SLOT_ELEMS;
        bf16_t*       zslot = hslots + (size_t)((t + 2) & (NSLOT - 1)) * SLOT_ELEMS;

        // ---- h GEMM with self-validating loads: a 16-bit value of 0x0000
        // means "not yet written" (producers store -0.0 for true zeros).
        // The successful data load IS the synchronization — no flags,
        // no producer drain, no separate poll RT. (t=0: h_0 = 0, skip.)
        if (t > 0) {
            const bf16_t* hb = hprev + (size_t)(r0 + lm) * DLAT + wv * 256 + lq * 8;
            bf16x8 ha[8];
            while (true) {
#pragma unroll
                for (int ks = 0; ks < 8; ++ks) ha[ks] = ldh16_sc1(hb + ks * 32);
                asm volatile("s_waitcnt vmcnt(0)" ::: "memory");
                __builtin_amdgcn_sched_barrier(0);
                bool ok = true;
#pragma unroll
                for (int ks = 0; ks < 8; ++ks) {
                    const u32x4 w = __builtin_bit_cast(u32x4, ha[ks]);
#pragma unroll
                    for (int i = 0; i < 4; ++i) {
                        ok = ok && ((w[i] & 0xFFFFu) != 0u) && ((w[i] & 0xFFFF0000u) != 0u);
                    }
                }
                if (__all(ok)) break;
            }
#pragma unroll
            for (int ks = 0; ks < 8; ++ks) {
                const int kh = wv * 256 + ks * 32;
#pragma unroll
                for (int cf = 0; cf < 4; ++cf) {
                    const bf16x8 b = ldsHW(ldsraw, cf * 16 + lm, kh, lq);
                    acc[cf] = __builtin_amdgcn_mfma_f32_16x16x32_bf16(ha[ks], b, acc[cf], 0, 0, 0);
                }
            }
        }

        // ---- cross-wave K-reduction via LDS ----
        // acc[cf][i] = (row = lq*4+i, col = cf*16+lm)
#pragma unroll
        for (int cf = 0; cf < 4; ++cf)
            *(f32x4*)&part[(wv * 64 + cf * 16 + lm) * 20 + lq * 4] = acc[cf];
        bar_lds();   // barrier #1: partials visible (no vmcnt drain)

        float gs[4];
#pragma unroll
        for (int g = 0; g < 4; ++g) {
            const int c = g * 16 + jj;
            gs[g] = part[(0 * 64 + c) * 20 + row_l] + part[(1 * 64 + c) * 20 + row_l]
                  + part[(2 * 64 + c) * 20 + row_l] + part[(3 * 64 + c) * 20 + row_l]
                  + bias_r[g];
        }
        const float ft = sigmoidf_(gs[0]);
        const float it = sigmoidf_(gs[1]);
        const float ot = sigmoidf_(gs[2]);
        const float ut = tanh_fast(gs[3]);
        cst = ft * cst + it * ut;
        const float hv = ot * tanh_fast(cst);

        // ---- publish h_{t+1}: per-thread 2B sc1 store, +0.0 -> -0.0 so the
        // bit pattern 0x0000 never occurs in published data (bit-exact) ----
        {
            uint32_t hbits = (uint32_t)__builtin_bit_cast(uint16_t, (bf16_t)hv);
            if (hbits == 0u) hbits = 0x8000u;   // -0.0, numerically identical
            sth2u(hnext + (size_t)(r0 + row_l) * DLAT + j0 + jj, hbits);
        }
        // zero-ahead: clear our stripe of the slot that will carry h_{t+2}
        // (its previous content h_{t-62} was consumed ~62 steps ago; our own
        // republish at step t+1 is ordered behind next step's vmcnt(0))
        sth2u(zslot + (size_t)(r0 + row_l) * DLAT + j0 + jj, 0u);

        bar_lds();   // barrier #2: part reads complete (WAR); stores keep flying

        // out store (cached path)
        out[((size_t)t * BATCH + r0 + row_l) * DLAT + j0 + jj] = hv;

        // ---- overlap: x_{t+1} GEMM into fresh acc ----
#pragma unroll
        for (int cf = 0; cf < 4; ++cf) acc[cf] = (f32x4){0.f, 0.f, 0.f, 0.f};
        if (t + 1 < T_STEPS) {
            const bf16_t* xa = xb + (size_t)(t + 1) * (BATCH * DIN)
                             + (size_t)(r0 + lm) * DIN + wv * 128 + lq * 8;
#pragma unroll
            for (int ks = 0; ks < 4; ++ks) {
                const bf16x8 a = *(const bf16x8*)(xa + ks * 32);
#pragma unroll
                for (int cf = 0; cf < 4; ++cf) {
                    const bf16x8 b = *(const bf16x8*)(wx_base + (ks * 4 + cf) * 512 + lane * 8);
                    acc[cf] = __builtin_amdgcn_mfma_f32_16x16x32_bf16(a, b, acc[cf], 0, 0, 0);
                }
            }
        }
    }
}

extern "C" void kernel_launch(void* const* d_in, const int* in_sizes, int n_in,
                              void* d_out, int out_size, void* d_ws, size_t ws_size,
                              hipStream_t stream) {
    const float* x  = (const float*)d_in[0];
    const float* Wf = (const float*)d_in[1];
    const float* Wi = (const float*)d_in[2];
    const float* Wo = (const float*)d_in[3];
    const float* Wu = (const float*)d_in[4];
    const float* bf = (const float*)d_in[5];
    const float* bi = (const float*)d_in[6];
    const float* bo = (const float*)d_in[7];
    const float* bu = (const float*)d_in[8];
    float* out = (float*)d_out;

    char* ws = (char*)d_ws;
    bf16_t* xb     = (bf16_t*)(ws + XB_OFF);
    bf16_t* wxt    = (bf16_t*)(ws + WXT_OFF);
    bf16_t* hslots = (bf16_t*)(ws + HS_OFF);

    // zero all h slots (the "0x0000 = unwritten" invariant), every replay
    (void)hipMemsetAsync(ws + HS_OFF, 0, MEMSET_BYTES, stream);

    // convert x -> bf16; transpose x-weights into frag order
    xconv_kernel<<<16384, 256, 0, stream>>>(x, xb);
    wxt_prep<<<1024, 256, 0, stream>>>(Wf, Wi, Wo, Wu, wxt);

    (void)hipFuncSetAttribute((const void*)lstm_main,
                              hipFuncAttributeMaxDynamicSharedMemorySize, LDS_BYTES);

    lstm_main<<<NWG, 256, LDS_BYTES, stream>>>(Wf, Wi, Wo, Wu, bf, bi, bo, bu,
                                               xb, wxt, hslots, out);
}

// Round 16
// 2013.611 us; speedup vs baseline: 2.0243x; 1.0294x over previous
//
#include <hip/hip_runtime.h>
#include <hip/hip_bf16.h>
#include <stdint.h>

#define T_STEPS 512
#define BATCH   64
#define DIN     512
#define DLAT    1024
#define NWG     256          // 64 col-tiles x 4 row-blocks

typedef __bf16 bf16_t;
typedef __bf16 bf16x4 __attribute__((ext_vector_type(4)));
typedef __bf16 bf16x8 __attribute__((ext_vector_type(8)));
typedef float  f32x4  __attribute__((ext_vector_type(4)));

// ---- workspace layout (bytes) ----
#define XB_OFF     0u                        // bf16 x [512][64][512] = 33,554,432
#define WXT_OFF    33554432u                 // bf16 x-weights frag-ordered = 4,194,304
#define FLAGS_OFF  (WXT_OFF + 4194304u)      // u32 flags[513][256] = 525,312
#define HS_OFF     (FLAGS_OFF + 525312u)     // bf16 h ring [2][64][1024] = 262,144
#define SLOT_ELEMS 65536
#define MEMSET_BYTES (525312u + 262144u)     // flags + both h slots

// ---- LDS layout (bytes) ----
#define HW_OFF_B   0          // h-weights [64 cols][1024 k] bf16, swizzled = 131,072
#define PART_OFF_B 131072     // f32 [4 waves][64 cols][20 rows-pad] = 20,480
#define PUB_OFF_B  151552     // bf16 [16 rows][16 j] = 512
#define LDS_BYTES  152064     // forces 1 WG/CU

__global__ void xconv_kernel(const float* __restrict__ x, bf16_t* __restrict__ xb) {
    size_t i = ((size_t)blockIdx.x * 256 + threadIdx.x) * 4;
    const float4 v = *(const float4*)(x + i);
    bf16x4 o;
    o[0] = (bf16_t)v.x; o[1] = (bf16_t)v.y; o[2] = (bf16_t)v.z; o[3] = (bf16_t)v.w;
    *(bf16x4*)(xb + i) = o;
}

// x-weight prep: wxt frag order (verified R10). Chunk gid (16B): lane = gid&63,
// f = gid>>6; cf = f&3 (gate), ks = (f>>2)&3, wv = (f>>4)&3, ct = f>>6.
__global__ void wxt_prep(const float* __restrict__ Wf, const float* __restrict__ Wi,
                         const float* __restrict__ Wo, const float* __restrict__ Wu,
                         bf16_t* __restrict__ wxt) {
    const int gid  = blockIdx.x * 256 + threadIdx.x;   // 0..262143
    const int lane = gid & 63;
    const int f    = gid >> 6;
    const int cf   = f & 3;
    const int ks   = (f >> 2) & 3;
    const int wv   = (f >> 4) & 3;
    const int ct   = f >> 6;
    const float* Wg = (cf == 0) ? Wf : (cf == 1) ? Wi : (cf == 2) ? Wo : Wu;
    const int k0 = wv * 128 + ks * 32 + (lane >> 4) * 8;
    const int j  = ct * 16 + (lane & 15);
    bf16x8 v;
#pragma unroll
    for (int e = 0; e < 8; ++e) v[e] = (bf16_t)Wg[(size_t)(k0 + e) * DLAT + j];
    *(bf16x8*)(wxt + (size_t)gid * 8) = v;
}

__device__ __forceinline__ float rcp_(float x) { return __builtin_amdgcn_rcpf(x); }
__device__ __forceinline__ float sigmoidf_(float v) { return rcp_(1.f + __expf(-v)); }
__device__ __forceinline__ float tanh_fast(float x) {
    const float ax = fabsf(x);
    const float e  = __expf(-2.f * ax);
    const float t  = (1.f - e) * rcp_(1.f + e);
    return copysignf(t, x);
}

// h-weight frag from LDS: col c, h-k base kh (lane adds lq*8)
__device__ __forceinline__ bf16x8 ldsHW(const char* lds, int c, int kh, int lq) {
    const uint32_t off = (uint32_t)(c * 2048 + kh * 2 + lq * 16)
                       ^ (uint32_t)((c & 7) << 4);
    return *(const bf16x8*)(lds + HW_OFF_B + off);
}

// sc1 (MALL-coherent) 16B load, issued without wait (h path — proven protocol)
__device__ __forceinline__ bf16x8 ldh16_sc1(const bf16_t* p) {
    f32x4 r;
    asm volatile("global_load_dwordx4 %0, %1, off sc1"
                 : "=v"(r) : "v"(p) : "memory");
    return __builtin_bit_cast(bf16x8, r);
}

// device-scope 16B write-through store (publish)
__device__ __forceinline__ void sth16(bf16_t* p, bf16x8 v) {
    const f32x4 d = __builtin_bit_cast(f32x4, v);
    asm volatile("global_store_dwordx4 %0, %1, off sc1"
                 :: "v"(p), "v"(d) : "memory");
}

__device__ __forceinline__ void stflag(uint32_t* p, uint32_t v) {
    asm volatile("global_store_dword %0, %1, off sc1" :: "v"(p), "v"(v) : "memory");
}

__launch_bounds__(256, 1)
__global__ void lstm_main(const float* __restrict__ Wf, const float* __restrict__ Wi,
                          const float* __restrict__ Wo, const float* __restrict__ Wu,
                          const float* __restrict__ bfp, const float* __restrict__ bip,
                          const float* __restrict__ bop, const float* __restrict__ bup,
                          const bf16_t* __restrict__ xb,
                          const bf16_t* __restrict__ wxt,
                          bf16_t* __restrict__ hslots,
                          uint32_t* __restrict__ flags,
                          float* __restrict__ out) {
    extern __shared__ char ldsraw[];
    float*  part = (float*)(ldsraw + PART_OFF_B);   // [4][64 cols][20 rows]
    bf16_t* pub  = (bf16_t*)(ldsraw + PUB_OFF_B);   // [16 rows][16 j]

    const int tid  = threadIdx.x;
    const int wv   = tid >> 6;       // wave = k-slice
    const int lane = tid & 63;
    const int lm   = lane & 15;
    const int lq   = lane >> 4;
    const int rb   = blockIdx.x & 3;    // row-block: rows [rb*16, +16)
    const int ct   = blockIdx.x >> 2;   // col-tile: j [ct*16, +16), all 4 gates
    const int r0   = rb * 16;
    const int j0   = ct * 16;

    // ---- one-time: h-weights -> LDS [64 cols][1024 k] bf16, swizzled ----
    {
        const int c    = tid & 63;
        const int gate = c >> 4;
        const int jj_  = c & 15;
        const float* Wg = (gate == 0) ? Wf : (gate == 1) ? Wi : (gate == 2) ? Wo : Wu;
        const float* src = Wg + (size_t)512 * DLAT + (j0 + jj_);
        for (int kb = tid >> 6; kb < 128; kb += 4) {
            const int k0 = kb * 8;
            bf16x8 v;
#pragma unroll
            for (int e = 0; e < 8; ++e) v[e] = (bf16_t)src[(size_t)(k0 + e) * DLAT];
            const uint32_t a = (uint32_t)(c * 2048 + kb * 16) ^ (uint32_t)((c & 7) << 4);
            *(bf16x8*)(ldsraw + HW_OFF_B + a) = v;
        }
    }

    // elementwise ownership: tid = row_l*16 + jj
    const int row_l = tid >> 4;          // 0..15
    const int jj    = tid & 15;          // 0..15
    const float bias_r[4] = { bfp[j0 + jj], bip[j0 + jj], bop[j0 + jj], bup[j0 + jj] };
    float cst = 0.f;

    // per-wave x-weight base (frag-ordered, cached reads — read-only, safe)
    const bf16_t* wx_base = wxt + (size_t)((ct * 4 + wv) * 16) * 512;

    __syncthreads();   // weights visible

    // ---- stagger the 4 independent rb-chains by ~1 us each so their
    // per-step sc1 h-load bursts hit the MALL in separate windows
    // (s_sleep N sleeps 64*N cycles; 38*64 = 2432 cy ~= 1.0 us @2.4GHz).
    // Chains have identical cadence, so the offsets persist. ----
    if (rb >= 1) __builtin_amdgcn_s_sleep(38);
    if (rb >= 2) __builtin_amdgcn_s_sleep(38);
    if (rb >= 3) __builtin_amdgcn_s_sleep(38);

    f32x4 acc[4];
#pragma unroll
    for (int cf = 0; cf < 4; ++cf) acc[cf] = (f32x4){0.f, 0.f, 0.f, 0.f};

    // ---- prologue: x_0 GEMM (wave x-k slice [wv*128, +128)) ----
    {
        const bf16_t* xa = xb + (size_t)(r0 + lm) * DIN + wv * 128 + lq * 8;
#pragma unroll
        for (int ks = 0; ks < 4; ++ks) {
            const bf16x8 a = *(const bf16x8*)(xa + ks * 32);
#pragma unroll
            for (int cf = 0; cf < 4; ++cf) {
                const bf16x8 b = *(const bf16x8*)(wx_base + (ks * 4 + cf) * 512 + lane * 8);
                acc[cf] = __builtin_amdgcn_mfma_f32_16x16x32_bf16(a, b, acc[cf], 0, 0, 0);
            }
        }
    }

    for (int t = 0; t < T_STEPS; ++t) {
        const bf16_t* hprev = hslots + (size_t)(t & 1) * SLOT_ELEMS;
        bf16_t*       hnext = hslots + (size_t)((t + 1) & 1) * SLOT_ELEMS;

        // ---- narrowed poll: this WG reads h rows [r0,+16) only, produced by
        // the 64 WGs with the same rb (bid = lane*4 + rb). Readers of our own
        // h region form exactly this same set, so 2-slot reuse stays safe
        // (a producer's flag follows its reads). ----
        if (t > 0) {
            const uint32_t* fp = flags + (size_t)t * 256 + (uint32_t)(lane * 4 + rb);
            while (true) {
                uint32_t v;
                asm volatile("global_load_dword %0, %1, off sc1\n\ts_waitcnt vmcnt(0)"
                             : "=v"(v) : "v"(fp) : "memory");
                if (__all(v == 1u)) break;
                __builtin_amdgcn_s_sleep(1);
            }
            asm volatile("" ::: "memory");
        } else {
            asm volatile("s_waitcnt vmcnt(0)" ::: "memory");   // clean vmcnt baseline
        }

        // ---- h GEMM: 8 sc1 16B loads (16 rows x 256 k per wave), two-stage
        // vmcnt; B-frags from LDS ----
        {
            const bf16_t* hb = hprev + (size_t)(r0 + lm) * DLAT + wv * 256 + lq * 8;
            bf16x8 ha[8];
#pragma unroll
            for (int ks = 0; ks < 8; ++ks) ha[ks] = ldh16_sc1(hb + ks * 32);
            asm volatile("s_waitcnt vmcnt(4)" ::: "memory");
            __builtin_amdgcn_sched_barrier(0);
#pragma unroll
            for (int ks = 0; ks < 4; ++ks) {
                const int kh = wv * 256 + ks * 32;
#pragma unroll
                for (int cf = 0; cf < 4; ++cf) {
                    const bf16x8 b = ldsHW(ldsraw, cf * 16 + lm, kh, lq);
                    acc[cf] = __builtin_amdgcn_mfma_f32_16x16x32_bf16(ha[ks], b, acc[cf], 0, 0, 0);
                }
            }
            asm volatile("s_waitcnt vmcnt(0)" ::: "memory");
            __builtin_amdgcn_sched_barrier(0);
#pragma unroll
            for (int ks = 4; ks < 8; ++ks) {
                const int kh = wv * 256 + ks * 32;
#pragma unroll
                for (int cf = 0; cf < 4; ++cf) {
                    const bf16x8 b = ldsHW(ldsraw, cf * 16 + lm, kh, lq);
                    acc[cf] = __builtin_amdgcn_mfma_f32_16x16x32_bf16(ha[ks], b, acc[cf], 0, 0, 0);
                }
            }
        }

        // ---- cross-wave K-reduction via LDS ----
        // acc[cf][i] = (row = lq*4+i, col = cf*16+lm)
#pragma unroll
        for (int cf = 0; cf < 4; ++cf)
            *(f32x4*)&part[(wv * 64 + cf * 16 + lm) * 20 + lq * 4] = acc[cf];
        __syncthreads();   // barrier #1

        float gs[4];
#pragma unroll
        for (int g = 0; g < 4; ++g) {
            const int c = g * 16 + jj;
            gs[g] = part[(0 * 64 + c) * 20 + row_l] + part[(1 * 64 + c) * 20 + row_l]
                  + part[(2 * 64 + c) * 20 + row_l] + part[(3 * 64 + c) * 20 + row_l]
                  + bias_r[g];
        }
        const float ft = sigmoidf_(gs[0]);
        const float it = sigmoidf_(gs[1]);
        const float ot = sigmoidf_(gs[2]);
        const float ut = tanh_fast(gs[3]);
        cst = ft * cst + it * ut;
        const float hv = ot * tanh_fast(cst);

        pub[row_l * 16 + jj] = (bf16_t)hv;
        __syncthreads();   // barrier #2: pub visible + part reads complete

        // ---- publish: 16 rows x 32B = 32 lanes x 16B sc1 stores (wave 0) ----
        if (tid < 32) {
            const int r2 = tid >> 1, half = tid & 1;
            const bf16x8 hrow = *(const bf16x8*)(pub + r2 * 16 + half * 8);
            sth16(hnext + (size_t)(r0 + r2) * DLAT + j0 + half * 8, hrow);
        }
        if (wv == 0) {
            asm volatile("s_waitcnt vmcnt(0)" ::: "memory");   // h stores at MALL
        }
        if (tid == 0)
            stflag(flags + (size_t)(t + 1) * 256 + blockIdx.x, 1u);

        // out store (cached path) after the publish chain
        out[((size_t)t * BATCH + r0 + row_l) * DLAT + j0 + jj] = hv;

        // ---- overlap: x_{t+1} GEMM into fresh acc while others finish ----
#pragma unroll
        for (int cf = 0; cf < 4; ++cf) acc[cf] = (f32x4){0.f, 0.f, 0.f, 0.f};
        if (t + 1 < T_STEPS) {
            const bf16_t* xa = xb + (size_t)(t + 1) * (BATCH * DIN)
                             + (size_t)(r0 + lm) * DIN + wv * 128 + lq * 8;
#pragma unroll
            for (int ks = 0; ks < 4; ++ks) {
                const bf16x8 a = *(const bf16x8*)(xa + ks * 32);
#pragma unroll
                for (int cf = 0; cf < 4; ++cf) {
                    const bf16x8 b = *(const bf16x8*)(wx_base + (ks * 4 + cf) * 512 + lane * 8);
                    acc[cf] = __builtin_amdgcn_mfma_f32_16x16x32_bf16(a, b, acc[cf], 0, 0, 0);
                }
            }
        }
    }
}

extern "C" void kernel_launch(void* const* d_in, const int* in_sizes, int n_in,
                              void* d_out, int out_size, void* d_ws, size_t ws_size,
                              hipStream_t stream) {
    const float* x  = (const float*)d_in[0];
    const float* Wf = (const float*)d_in[1];
    const float* Wi = (const float*)d_in[2];
    const float* Wo = (const float*)d_in[3];
    const float* Wu = (const float*)d_in[4];
    const float* bf = (const float*)d_in[5];
    const float* bi = (const float*)d_in[6];
    const float* bo = (const float*)d_in[7];
    const float* bu = (const float*)d_in[8];
    float* out = (float*)d_out;

    char* ws = (char*)d_ws;
    bf16_t*   xb     = (bf16_t*)(ws + XB_OFF);
    bf16_t*   wxt    = (bf16_t*)(ws + WXT_OFF);
    uint32_t* flags  = (uint32_t*)(ws + FLAGS_OFF);
    bf16_t*   hslots = (bf16_t*)(ws + HS_OFF);

    // zero flags + both h slots (every launch/replay)
    (void)hipMemsetAsync(ws + FLAGS_OFF, 0, MEMSET_BYTES, stream);

    // convert x -> bf16; transpose x-weights into frag order
    xconv_kernel<<<16384, 256, 0, stream>>>(x, xb);
    wxt_prep<<<1024, 256, 0, stream>>>(Wf, Wi, Wo, Wu, wxt);

    (void)hipFuncSetAttribute((const void*)lstm_main,
                              hipFuncAttributeMaxDynamicSharedMemorySize, LDS_BYTES);

    lstm_main<<<NWG, 256, LDS_BYTES, stream>>>(Wf, Wi, Wo, Wu, bf, bi, bo, bu,
                                               xb, wxt, hslots, flags, out);
}

// Round 17
// 1553.919 us; speedup vs baseline: 2.6231x; 1.2958x over previous
//
#include <hip/hip_runtime.h>
#include <hip/hip_bf16.h>
#include <stdint.h>

#define T_STEPS 512
#define BATCH   64
#define DIN     512
#define DLAT    1024
#define NWG     256          // 64 col-tiles x 4 row-blocks
#define NSLOT   64           // h slot ring (zero = not-yet-written protocol)

typedef __bf16 bf16_t;
typedef __bf16 bf16x4 __attribute__((ext_vector_type(4)));
typedef __bf16 bf16x8 __attribute__((ext_vector_type(8)));
typedef float  f32x4  __attribute__((ext_vector_type(4)));
typedef uint32_t u32x4 __attribute__((ext_vector_type(4)));

// ---- workspace layout (bytes) ----
#define XB_OFF     0u                        // bf16 x [512][64][512] = 33,554,432
#define WXT_OFF    33554432u                 // bf16 x-weights frag-ordered = 4,194,304
#define HWT_OFF    (WXT_OFF + 4194304u)      // bf16 h-weights frag-ordered = 8,388,608
#define HS_OFF     (HWT_OFF + 8388608u)      // bf16 h slots [64][64][1024] = 8,388,608
#define SLOT_ELEMS 65536
#define MEMSET_BYTES 8388608u                // all 64 h slots -> 0 every launch

// ---- LDS (only part-exchange used; large request forces 1 WG/CU) ----
#define PART_OFF_B 0          // f32 [4 waves][64 cols][20 rows-pad] = 20,480
#define LDS_BYTES  131072     // forces 1 WG/CU (occupancy clamp)

__global__ void xconv_kernel(const float* __restrict__ x, bf16_t* __restrict__ xb) {
    size_t i = ((size_t)blockIdx.x * 256 + threadIdx.x) * 4;
    const float4 v = *(const float4*)(x + i);
    bf16x4 o;
    o[0] = (bf16_t)v.x; o[1] = (bf16_t)v.y; o[2] = (bf16_t)v.z; o[3] = (bf16_t)v.w;
    *(bf16x4*)(xb + i) = o;
}

// x-weight prep (frag order, verified R10-R16): frag f = gid>>6;
// cf = f&3 (gate), ks = (f>>2)&3, wv = (f>>4)&3, ct = f>>6.
__global__ void wxt_prep(const float* __restrict__ Wf, const float* __restrict__ Wi,
                         const float* __restrict__ Wo, const float* __restrict__ Wu,
                         bf16_t* __restrict__ wxt) {
    const int gid  = blockIdx.x * 256 + threadIdx.x;   // 0..262143
    const int lane = gid & 63;
    const int f    = gid >> 6;
    const int cf   = f & 3;
    const int ks   = (f >> 2) & 3;
    const int wv   = (f >> 4) & 3;
    const int ct   = f >> 6;
    const float* Wg = (cf == 0) ? Wf : (cf == 1) ? Wi : (cf == 2) ? Wo : Wu;
    const int k0 = wv * 128 + ks * 32 + (lane >> 4) * 8;
    const int j  = ct * 16 + (lane & 15);
    bf16x8 v;
#pragma unroll
    for (int e = 0; e < 8; ++e) v[e] = (bf16_t)Wg[(size_t)(k0 + e) * DLAT + j];
    *(bf16x8*)(wxt + (size_t)gid * 8) = v;
}

// h-weight prep (frag order): frag f = gid>>6 (0..8191);
// cf = f&3 (gate), ks = (f>>2)&7, wv = (f>>5)&3, ct = f>>7.
// elem e: W_gate[512 + wv*256 + ks*32 + (lane>>4)*8 + e][ct*16 + (lane&15)]
__global__ void hwt_prep(const float* __restrict__ Wf, const float* __restrict__ Wi,
                         const float* __restrict__ Wo, const float* __restrict__ Wu,
                         bf16_t* __restrict__ hwt) {
    const int gid  = blockIdx.x * 256 + threadIdx.x;   // 0..524287
    const int lane = gid & 63;
    const int f    = gid >> 6;
    const int cf   = f & 3;
    const int ks   = (f >> 2) & 7;
    const int wv   = (f >> 5) & 3;
    const int ct   = f >> 7;
    const float* Wg = (cf == 0) ? Wf : (cf == 1) ? Wi : (cf == 2) ? Wo : Wu;
    const int k0 = 512 + wv * 256 + ks * 32 + (lane >> 4) * 8;
    const int j  = ct * 16 + (lane & 15);
    bf16x8 v;
#pragma unroll
    for (int e = 0; e < 8; ++e) v[e] = (bf16_t)Wg[(size_t)(k0 + e) * DLAT + j];
    *(bf16x8*)(hwt + (size_t)gid * 8) = v;
}

__device__ __forceinline__ float rcp_(float x) { return __builtin_amdgcn_rcpf(x); }
__device__ __forceinline__ float sigmoidf_(float v) { return rcp_(1.f + __expf(-v)); }
__device__ __forceinline__ float tanh_fast(float x) {
    const float ax = fabsf(x);
    const float e  = __expf(-2.f * ax);
    const float t  = (1.f - e) * rcp_(1.f + e);
    return copysignf(t, x);
}

// sc1 (MALL-coherent) 16B load, issued without wait
__device__ __forceinline__ bf16x8 ldh16_sc1(const bf16_t* p) {
    f32x4 r;
    asm volatile("global_load_dwordx4 %0, %1, off sc1"
                 : "=v"(r) : "v"(p) : "memory");
    return __builtin_bit_cast(bf16x8, r);
}

// device-scope 2B write-through store
__device__ __forceinline__ void sth2u(bf16_t* p, uint32_t bits) {
    asm volatile("global_store_short %0, %1, off sc1"
                 :: "v"(p), "v"(bits) : "memory");
}

// raw WG barrier: LDS visibility only, does NOT drain vmcnt
__device__ __forceinline__ void bar_lds() {
    asm volatile("s_waitcnt lgkmcnt(0)" ::: "memory");
    __builtin_amdgcn_s_barrier();
    asm volatile("" ::: "memory");
}

__launch_bounds__(256, 1)
__global__ void lstm_main(const float* __restrict__ bfp, const float* __restrict__ bip,
                          const float* __restrict__ bop, const float* __restrict__ bup,
                          const bf16_t* __restrict__ xb,
                          const bf16_t* __restrict__ wxt,
                          const bf16_t* __restrict__ hwt,
                          bf16_t* __restrict__ hslots,
                          float* __restrict__ out) {
    extern __shared__ char ldsraw[];
    float* part = (float*)(ldsraw + PART_OFF_B);   // [4][64 cols][20 rows]

    const int tid  = threadIdx.x;
    const int wv   = tid >> 6;       // wave = k-slice
    const int lane = tid & 63;
    const int lm   = lane & 15;
    const int lq   = lane >> 4;
    const int rb   = blockIdx.x & 3;    // row-block: rows [rb*16, +16)
    const int ct   = blockIdx.x >> 2;   // col-tile: j [ct*16, +16), all 4 gates
    const int r0   = rb * 16;
    const int j0   = ct * 16;

    // elementwise ownership: tid = row_l*16 + jj
    const int row_l = tid >> 4;          // 0..15
    const int jj    = tid & 15;          // 0..15
    const float bias_r[4] = { bfp[j0 + jj], bip[j0 + jj], bop[j0 + jj], bup[j0 + jj] };
    float cst = 0.f;

    // ---- one-time: ALL weight fragments -> VGPRs (frag-ordered buffers,
    // contiguous 16B loads; 128 + 64 VGPRs of the 512 budget at 1 wave/SIMD).
    // Removes 32 ds_read_b128 + lgkm waits from every step's critical path.
    bf16x8 hwr[32];   // h-weights: [ks 0..7][cf 0..3]
    {
        const bf16_t* hw_base = hwt + (size_t)((ct * 4 + wv) * 32) * 512;
#pragma unroll
        for (int f = 0; f < 32; ++f)
            hwr[f] = *(const bf16x8*)(hw_base + (size_t)f * 512 + lane * 8);
    }
    bf16x8 wxr[16];   // x-weights: [ks 0..3][cf 0..3]
    {
        const bf16_t* wx_base = wxt + (size_t)((ct * 4 + wv) * 16) * 512;
#pragma unroll
        for (int f = 0; f < 16; ++f)
            wxr[f] = *(const bf16x8*)(wx_base + (size_t)f * 512 + lane * 8);
    }

    f32x4 acc[4];
#pragma unroll
    for (int cf = 0; cf < 4; ++cf) acc[cf] = (f32x4){0.f, 0.f, 0.f, 0.f};

    // ---- prologue: x_0 GEMM (wave x-k slice [wv*128, +128)) ----
    {
        const bf16_t* xa = xb + (size_t)(r0 + lm) * DIN + wv * 128 + lq * 8;
#pragma unroll
        for (int ks = 0; ks < 4; ++ks) {
            const bf16x8 a = *(const bf16x8*)(xa + ks * 32);
#pragma unroll
            for (int cf = 0; cf < 4; ++cf)
                acc[cf] = __builtin_amdgcn_mfma_f32_16x16x32_bf16(a, wxr[ks * 4 + cf], acc[cf], 0, 0, 0);
        }
    }

    for (int t = 0; t < T_STEPS; ++t) {
        const bf16_t* hprev = hslots + (size_t)(t & (NSLOT - 1)) * SLOT_ELEMS;
        bf16_t*       hnext = hslots + (size_t)((t + 1) & (NSLOT - 1)) * SLOT_ELEMS;
        bf16_t*       zslot = hslots + (size_t)((t + 2) & (NSLOT - 1)) * SLOT_ELEMS;

        // ---- h GEMM with self-validating loads (R13-proven): 0x0000 means
        // "not yet written" (producers store -0.0 for true zeros). The
        // successful data load IS the synchronization. (t=0: h_0 = 0, skip.)
        if (t > 0) {
            const bf16_t* hb = hprev + (size_t)(r0 + lm) * DLAT + wv * 256 + lq * 8;
            bf16x8 ha[8];
            while (true) {
#pragma unroll
                for (int ks = 0; ks < 8; ++ks) ha[ks] = ldh16_sc1(hb + ks * 32);
                asm volatile("s_waitcnt vmcnt(0)" ::: "memory");
                __builtin_amdgcn_sched_barrier(0);
                bool ok = true;
#pragma unroll
                for (int ks = 0; ks < 8; ++ks) {
                    const u32x4 w = __builtin_bit_cast(u32x4, ha[ks]);
#pragma unroll
                    for (int i = 0; i < 4; ++i)
                        ok = ok && ((w[i] & 0xFFFFu) != 0u) && ((w[i] & 0xFFFF0000u) != 0u);
                }
                if (__all(ok)) break;
            }
            // pure-register MFMAs (weights already in VGPRs)
#pragma unroll
            for (int ks = 0; ks < 8; ++ks)
#pragma unroll
                for (int cf = 0; cf < 4; ++cf)
                    acc[cf] = __builtin_amdgcn_mfma_f32_16x16x32_bf16(ha[ks], hwr[ks * 4 + cf], acc[cf], 0, 0, 0);
        }

        // ---- cross-wave K-reduction via LDS ----
        // acc[cf][i] = (row = lq*4+i, col = cf*16+lm)
#pragma unroll
        for (int cf = 0; cf < 4; ++cf)
            *(f32x4*)&part[(wv * 64 + cf * 16 + lm) * 20 + lq * 4] = acc[cf];
        bar_lds();   // barrier #1: partials visible (no vmcnt drain)

        float gs[4];
#pragma unroll
        for (int g = 0; g < 4; ++g) {
            const int c = g * 16 + jj;
            gs[g] = part[(0 * 64 + c) * 20 + row_l] + part[(1 * 64 + c) * 20 + row_l]
                  + part[(2 * 64 + c) * 20 + row_l] + part[(3 * 64 + c) * 20 + row_l]
                  + bias_r[g];
        }
        const float ft = sigmoidf_(gs[0]);
        const float it = sigmoidf_(gs[1]);
        const float ot = sigmoidf_(gs[2]);
        const float ut = tanh_fast(gs[3]);
        cst = ft * cst + it * ut;
        const float hv = ot * tanh_fast(cst);

        // ---- publish h_{t+1}: per-thread 2B sc1 store, +0.0 -> -0.0 so the
        // bit pattern 0x0000 never occurs in published data (bit-exact) ----
        {
            uint32_t hbits = (uint32_t)__builtin_bit_cast(uint16_t, (bf16_t)hv);
            if (hbits == 0u) hbits = 0x8000u;   // -0.0, numerically identical
            sth2u(hnext + (size_t)(r0 + row_l) * DLAT + j0 + jj, hbits);
        }
        // zero-ahead: clear our stripe of the slot that will carry h_{t+2}
        // (previous content consumed ~62 steps ago; same-rb chains provably
        // within 1 step of each other — R13 argument)
        sth2u(zslot + (size_t)(r0 + row_l) * DLAT + j0 + jj, 0u);

        bar_lds();   // barrier #2 (WAR on part); stores keep flying

        // out store (cached path)
        out[((size_t)t * BATCH + r0 + row_l) * DLAT + j0 + jj] = hv;

        // ---- overlap: x_{t+1} GEMM into fresh acc ----
#pragma unroll
        for (int cf = 0; cf < 4; ++cf) acc[cf] = (f32x4){0.f, 0.f, 0.f, 0.f};
        if (t + 1 < T_STEPS) {
            const bf16_t* xa = xb + (size_t)(t + 1) * (BATCH * DIN)
                             + (size_t)(r0 + lm) * DIN + wv * 128 + lq * 8;
#pragma unroll
            for (int ks = 0; ks < 4; ++ks) {
                const bf16x8 a = *(const bf16x8*)(xa + ks * 32);
#pragma unroll
                for (int cf = 0; cf < 4; ++cf)
                    acc[cf] = __builtin_amdgcn_mfma_f32_16x16x32_bf16(a, wxr[ks * 4 + cf], acc[cf], 0, 0, 0);
            }
        }
    }
}

extern "C" void kernel_launch(void* const* d_in, const int* in_sizes, int n_in,
                              void* d_out, int out_size, void* d_ws, size_t ws_size,
                              hipStream_t stream) {
    const float* x  = (const float*)d_in[0];
    const float* Wf = (const float*)d_in[1];
    const float* Wi = (const float*)d_in[2];
    const float* Wo = (const float*)d_in[3];
    const float* Wu = (const float*)d_in[4];
    const float* bf = (const float*)d_in[5];
    const float* bi = (const float*)d_in[6];
    const float* bo = (const float*)d_in[7];
    const float* bu = (const float*)d_in[8];
    float* out = (float*)d_out;

    char* ws = (char*)d_ws;
    bf16_t* xb     = (bf16_t*)(ws + XB_OFF);
    bf16_t* wxt    = (bf16_t*)(ws + WXT_OFF);
    bf16_t* hwt    = (bf16_t*)(ws + HWT_OFF);
    bf16_t* hslots = (bf16_t*)(ws + HS_OFF);

    // zero all h slots (0x0000 = unwritten invariant), every replay
    (void)hipMemsetAsync(ws + HS_OFF, 0, MEMSET_BYTES, stream);

    // convert x -> bf16; transpose weights into frag order
    xconv_kernel<<<16384, 256, 0, stream>>>(x, xb);
    wxt_prep<<<1024, 256, 0, stream>>>(Wf, Wi, Wo, Wu, wxt);
    hwt_prep<<<2048, 256, 0, stream>>>(Wf, Wi, Wo, Wu, hwt);

    (void)hipFuncSetAttribute((const void*)lstm_main,
                              hipFuncAttributeMaxDynamicSharedMemorySize, LDS_BYTES);

    lstm_main<<<NWG, 256, LDS_BYTES, stream>>>(bf, bi, bo, bu,
                                               xb, wxt, hwt, hslots, out);
}